// Round 17
// baseline (183.206 us; speedup 1.0000x reference)
//
#include <hip/hip_runtime.h>
#include <hip/hip_bf16.h>
#include <stdint.h>

// B=4, T=2048, D_MODEL=1024, H=16, hd=64
// Q/K token-major: [B*T, 1024], head h at cols h*64..h*64+63.
// V is stored TRANSPOSED: Vt[bh][d][t] = Vt[bh*131072 + d*2048 + t] (bf16).
// W_Q is pre-scaled by 0.125*log2(e) so softmax runs in log2 domain.

typedef __attribute__((ext_vector_type(8))) short short8;    // 8 x bf16 (4 VGPRs)
typedef __attribute__((ext_vector_type(4))) short short4v;
typedef __attribute__((ext_vector_type(4))) float floatx4;

#define LOG2E 1.4426950408889634f

__device__ __forceinline__ void gload_lds16(const void* g, void* l) {
  __builtin_amdgcn_global_load_lds(
      (const __attribute__((address_space(1))) void*)g,
      (__attribute__((address_space(3))) void*)l, 16, 0, 0);
}

__device__ __forceinline__ short f2bf(float f) {
  __hip_bfloat16 h = __float2bfloat16(f);
  return *reinterpret_cast<short*>(&h);
}

// ---------------- fp32 -> bf16 conversion ----------------
__global__ __launch_bounds__(256) void cvt_f32_bf16(const float* __restrict__ src,
                                                    short* __restrict__ dst, int n4,
                                                    float scale) {
  const int i = blockIdx.x * blockDim.x + threadIdx.x;
  if (i >= n4) return;
  const float4 v = reinterpret_cast<const float4*>(src)[i];
  short4v o;
  o.x = f2bf(v.x * scale); o.y = f2bf(v.y * scale);
  o.z = f2bf(v.z * scale); o.w = f2bf(v.w * scale);
  reinterpret_cast<short4v*>(dst)[i] = o;
}

// all 4 weights in one dispatch; dst buffers are contiguous (2 MiB apart).
__global__ __launch_bounds__(256) void cvt_weights(const float* __restrict__ wq,
                                                   const float* __restrict__ wk,
                                                   const float* __restrict__ wv,
                                                   const float* __restrict__ wo,
                                                   short* __restrict__ dst0,
                                                   float qscale) {
  const int y = blockIdx.y;
  const float* src = (y == 0) ? wq : (y == 1) ? wk : (y == 2) ? wv : wo;
  const float scale = (y == 0) ? qscale : 1.0f;
  short* dst = dst0 + (size_t)y * 1048576;
  const int i = blockIdx.x * blockDim.x + threadIdx.x;
  const float4 v = reinterpret_cast<const float4*>(src)[i];
  short4v o;
  o.x = f2bf(v.x * scale); o.y = f2bf(v.y * scale);
  o.z = f2bf(v.z * scale); o.w = f2bf(v.w * scale);
  reinterpret_cast<short4v*>(&dst[i * 4])[0] = o;
}

// ---- MERGED QKV GEMM (unchanged from round 16 — passing at 59.7us) ----
__global__ __launch_bounds__(512) void gemm_qkv(
    const short* __restrict__ xb, const short* __restrict__ wqkv,
    short* __restrict__ Qb, short* __restrict__ Kb, short* __restrict__ Vt) {
  __shared__ short lds_a[3][256 * 32];      // 48 KB
  __shared__ short lds_b[3][3 * 128 * 32];  // 72 KB : [buf][z][128r][32k]
  const int tid = threadIdx.x;
  const int lane = tid & 63;
  const int w = tid >> 6;                 // 0..7
  const int wm = w >> 1, wn = w & 1;      // 4M x 2N wave grid
  const int lrow = lane & 15, lgrp = lane >> 4;

  const int flat = blockIdx.x;            // 0..255
  const int n0 = (flat & 7) * 128;        // XCD-resident weight panel
  const int m0 = (flat >> 3) * 256;

  floatx4 acc[3][4][4] = {};

  const int srow = tid >> 2;              // 0..127
  const int scb = (tid & 3) ^ (srow & 3) ^ ((srow & 4) >> 1);
  const short* ag = xb + (size_t)(m0 + srow) * 1024 + scb * 8;
  const short* bg = wqkv + (size_t)(n0 + srow) * 1024 + scb * 8;

  auto stage5 = [&](short* la, short* lb) {
    gload_lds16(ag, la + tid * 8);
    gload_lds16(ag + 128 * 1024, la + (512 + tid) * 8);
    gload_lds16(bg,           lb + tid * 8);
    gload_lds16(bg + 1048576, lb + 4096 + tid * 8);
    gload_lds16(bg + 2097152, lb + 8192 + tid * 8);
    ag += 32; bg += 32;
  };

  const int slA = (lgrp ^ (lrow & 3) ^ ((lrow & 4) >> 1)) * 8;

  auto tile = [&](const short* la, const short* lb, short* na, short* nb, bool pf) {
    if (pf) stage5(na, nb);
    short8 af[4];
#pragma unroll
    for (int mf = 0; mf < 4; ++mf)
      af[mf] = *reinterpret_cast<const short8*>(
          &la[(wm * 64 + mf * 16 + lrow) * 32 + slA]);
#pragma unroll
    for (int z = 0; z < 3; ++z) {
      short8 bf[4];
#pragma unroll
      for (int nf = 0; nf < 4; ++nf)
        bf[nf] = *reinterpret_cast<const short8*>(
            &lb[z * 4096 + (wn * 64 + nf * 16 + lrow) * 32 + slA]);
      __builtin_amdgcn_s_setprio(1);
#pragma unroll
      for (int mf = 0; mf < 4; ++mf)
#pragma unroll
        for (int nf = 0; nf < 4; ++nf)
          acc[z][mf][nf] = __builtin_amdgcn_mfma_f32_16x16x32_bf16(
              af[mf], bf[nf], acc[z][mf][nf], 0, 0, 0);
      __builtin_amdgcn_s_setprio(0);
    }
  };

  auto tiletop = [&](int n) {
    __builtin_amdgcn_sched_barrier(0);
    if (n == 0)
      asm volatile("s_waitcnt vmcnt(0)" ::: "memory");
    else
      asm volatile("s_waitcnt vmcnt(5)" ::: "memory");
    __builtin_amdgcn_s_barrier();
    __builtin_amdgcn_sched_barrier(0);
  };

  stage5(lds_a[0], lds_b[0]);
  stage5(lds_a[1], lds_b[1]);

#pragma unroll 1
  for (int kt = 0; kt < 30; kt += 3) {
    tiletop(5); tile(lds_a[0], lds_b[0], lds_a[2], lds_b[2], true);
    tiletop(5); tile(lds_a[1], lds_b[1], lds_a[0], lds_b[0], true);
    tiletop(5); tile(lds_a[2], lds_b[2], lds_a[1], lds_b[1], true);
  }
  tiletop(5); tile(lds_a[0], lds_b[0], nullptr, nullptr, false);  // tile 30
  tiletop(0); tile(lds_a[1], lds_b[1], nullptr, nullptr, false);  // tile 31

#pragma unroll
  for (int z = 0; z < 3; ++z) {
#pragma unroll
    for (int mf = 0; mf < 4; ++mf) {
#pragma unroll
      for (int nf = 0; nf < 4; ++nf) {
        if (z == 2) {
          short4v pk;
#pragma unroll
          for (int r = 0; r < 4; ++r) pk[r] = f2bf(acc[z][mf][nf][r]);
          const int t0 = m0 + wm * 64 + mf * 16 + lgrp * 4;
          const int ch = n0 + wn * 64 + nf * 16 + lrow;
          const int bh = ((t0 >> 11) << 4) + (ch >> 6);
          *reinterpret_cast<short4v*>(
              &Vt[(size_t)bh * 131072 + (size_t)(ch & 63) * 2048 + (t0 & 2047)]) = pk;
        } else {
          short* C = (z == 0) ? Qb : Kb;
#pragma unroll
          for (int r = 0; r < 4; ++r) {
            const int grow = m0 + wm * 64 + mf * 16 + lgrp * 4 + r;
            const int gcol = n0 + wn * 64 + nf * 16 + lrow;
            C[(size_t)grow * 1024 + gcol] = f2bf(acc[z][mf][nf][r]);
          }
        }
      }
    }
  }
}

// ---- single-output GEMM (O-projection), r14 structure (unchanged, passing) ----
template <int MODE>
__device__ __forceinline__ void gemm256_body(const short* __restrict__ A,
                                             const short* __restrict__ B,
                                             void* __restrict__ Cout,
                                             int m0, int n0,
                                             short* __restrict__ la0,
                                             short* __restrict__ la1,
                                             short* __restrict__ la2,
                                             short* __restrict__ lb0,
                                             short* __restrict__ lb1,
                                             short* __restrict__ lb2) {
  const int tid = threadIdx.x;
  const int lane = tid & 63;
  const int w = tid >> 6;
  const int wm = w >> 1, wn = w & 1;
  const int lrow = lane & 15, lgrp = lane >> 4;

  floatx4 acc[4][4] = {};

  const int srow = tid >> 2;
  const int scb = (tid & 3) ^ (srow & 3) ^ ((srow & 4) >> 1);
  const short* ag = A + (size_t)(m0 + srow) * 1024 + scb * 8;
  const short* bg = B + (size_t)(n0 + srow) * 1024 + scb * 8;

  auto stage3 = [&](short* la, short* lb) {
    gload_lds16(ag, la + tid * 8);
    gload_lds16(ag + 128 * 1024, la + (512 + tid) * 8);
    gload_lds16(bg, lb + tid * 8);
    ag += 32; bg += 32;
  };

  const int slA = (lgrp ^ (lrow & 3) ^ ((lrow & 4) >> 1)) * 8;

  auto tile = [&](const short* la, const short* lb, short* na, short* nb, bool pf) {
    if (pf) stage3(na, nb);
    short8 af[4], bf[4];
#pragma unroll
    for (int mf = 0; mf < 4; ++mf) {
      const int row = wm * 64 + mf * 16 + lrow;
      af[mf] = *reinterpret_cast<const short8*>(&la[row * 32 + slA]);
    }
#pragma unroll
    for (int nf = 0; nf < 4; ++nf) {
      const int row = wn * 64 + nf * 16 + lrow;
      bf[nf] = *reinterpret_cast<const short8*>(&lb[row * 32 + slA]);
    }
    __builtin_amdgcn_s_setprio(1);
#pragma unroll
    for (int mf = 0; mf < 4; ++mf)
#pragma unroll
      for (int nf = 0; nf < 4; ++nf)
        acc[mf][nf] = __builtin_amdgcn_mfma_f32_16x16x32_bf16(af[mf], bf[nf], acc[mf][nf], 0, 0, 0);
    __builtin_amdgcn_s_setprio(0);
  };

  auto tiletop = [&](int n) {
    __builtin_amdgcn_sched_barrier(0);
    if (n == 0)
      asm volatile("s_waitcnt vmcnt(0)" ::: "memory");
    else
      asm volatile("s_waitcnt vmcnt(3)" ::: "memory");
    __builtin_amdgcn_s_barrier();
    __builtin_amdgcn_sched_barrier(0);
  };

  stage3(la0, lb0);
  stage3(la1, lb1);

#pragma unroll 1
  for (int kt = 0; kt < 30; kt += 3) {
    tiletop(3); tile(la0, lb0, la2, lb2, true);
    tiletop(3); tile(la1, lb1, la0, lb0, true);
    tiletop(3); tile(la2, lb2, la1, lb1, true);
  }
  tiletop(3); tile(la0, lb0, nullptr, nullptr, false);
  tiletop(0); tile(la1, lb1, nullptr, nullptr, false);

#pragma unroll
  for (int mf = 0; mf < 4; ++mf) {
#pragma unroll
    for (int nf = 0; nf < 4; ++nf) {
#pragma unroll
      for (int r = 0; r < 4; ++r) {
        const int grow = m0 + wm * 64 + mf * 16 + lgrp * 4 + r;
        const int gcol = n0 + wn * 64 + nf * 16 + lrow;
        if (MODE == 1)
          reinterpret_cast<short*>(Cout)[(size_t)grow * 1024 + gcol] = f2bf(acc[mf][nf][r]);
        else
          reinterpret_cast<float*>(Cout)[(size_t)grow * 1024 + gcol] = acc[mf][nf][r];
      }
    }
  }
}

__global__ __launch_bounds__(512) void gemm_out(const short* __restrict__ Ob,
                                                const short* __restrict__ wo,
                                                float* __restrict__ out) {
  __shared__ short lds_a[3][256 * 32];
  __shared__ short lds_b[3][128 * 32];
  const int flat = blockIdx.x;
  const int xcd = flat & 7, rest = flat >> 3;
  const int nblk = rest & 7, pg = rest >> 3;
  const int panel = pg * 8 + xcd;
  gemm256_body<0>(Ob, wo, out, panel * 256, nblk * 128,
                  lds_a[0], lds_a[1], lds_a[2], lds_b[0], lds_b[1], lds_b[2]);
}

// ---------------- flash attention (causal), bf16 in/out ----------------
// 256 threads = 4 waves; wave owns FOUR 16-row q-tiles (64 q rows) -> K/V
// fragment reads amortize over 4x MFMA vs 1-qtile (LDS-traffic amortization,
// proven lever in r15). Block covers 256 q rows; block p processes chunk
// (7-p) then chunk p -> exactly 36 KV-tile iterations per block. Grid 512:
// bh = flat & 63 (XCD locality), p = flat >> 6. LDS 64KB -> 2 blocks/CU.
// Per-wave diag: lastkb = 4qc + w (early-return guard; barriers in caller).
// Static-offset softmax: P = exp2(s) (log2 domain, scale cancels in /l).
__global__ __launch_bounds__(256, 2) void attn_fwd(const short* __restrict__ Q,
                                                   const short* __restrict__ K,
                                                   const short* __restrict__ Vt,
                                                   short* __restrict__ O) {
  __shared__ short lds_k[2][64 * 64];      // 16 KB
  __shared__ short lds_v[2][64 * 64];      // 16 KB : [d][k] swizzled
  __shared__ short lds_p[4][4][16 * 64];   // 32 KB : [wave][qt][16q][64k] swizzled

  const int tid = threadIdx.x;
  const int lane = tid & 63;
  const int w = tid >> 6;                // 0..3
  const int lrow = lane & 15, lgrp = lane >> 4;
  const int flat = blockIdx.x;
  const int bh = flat & 63;              // XCD-locality: same bh -> same XCD
  const int p = flat >> 6;               // 0..7 -> chunk pair (7-p, p)
  const int b = bh >> 4, h = bh & 15;

  const size_t base = (size_t)b * 2048 * 1024 + h * 64;
  const size_t vbase = (size_t)bh * 131072;

  const int srow = tid >> 3;                         // 0..31
  const int scb = (tid & 7) ^ (srow & 7);
  const size_t koff = (size_t)srow * 1024 + scb * 8;
  const size_t voff = (size_t)srow * 2048 + scb * 8;
  short* const kd0 = &lds_k[0][tid * 8];
  short* const kd1 = &lds_k[1][tid * 8];
  short* const vd0 = &lds_v[0][tid * 8];
  short* const vd1 = &lds_v[1][tid * 8];

  auto stageK = [&](short* ldst, const short* gsrc) {
    gload_lds16(gsrc, ldst);
    gload_lds16(gsrc + 32 * 1024, ldst + 2048);
  };
  auto stageV = [&](short* ldst, const short* gsrc) {
    gload_lds16(gsrc, ldst);
    gload_lds16(gsrc + 32 * 2048, ldst + 2048);
  };

#pragma unroll 1
  for (int pass = 0; pass < 2; ++pass) {
    const int qc = pass == 0 ? (7 - p) : p;    // 256-row q-chunk index
    const int qw = qc * 256 + w * 64;          // wave's first q row
    const int lastkb = 4 * qc + w;             // wave's diag KV tile
    const int nkb = 4 * qc + 4;                // block KV-tile count

    // Q B-frags: qf[qt][half] = Q[qw + qt*16 + lrow][half*32 + lgrp*8 .. +8]
    short8 qf[4][2];
#pragma unroll
    for (int qt = 0; qt < 4; ++qt) {
      const short* qp = Q + base + (size_t)(qw + qt * 16 + lrow) * 1024 + lgrp * 8;
      qf[qt][0] = *reinterpret_cast<const short8*>(qp);
      qf[qt][1] = *reinterpret_cast<const short8*>(qp + 32);
    }

    floatx4 oacc[4][4] = {};
    float lsum[4] = {0.f, 0.f, 0.f, 0.f};

    const short* kg = K + base + koff;
    const short* vg = Vt + vbase + voff;

    auto body = [&](int kb, const short* __restrict__ ldsk,
                    const short* __restrict__ ldsv) {
      if (kb > lastkb) return;   // wave done (barriers handled by caller)
      // ---- S^T = mfma(K, Q): s[qt][nf][r] = S[q][k] (log2 units)
      floatx4 s[4][4];
      __builtin_amdgcn_s_setprio(1);
#pragma unroll
      for (int nf = 0; nf < 4; ++nf) {
        const short8 kf0 = *reinterpret_cast<const short8*>(
            &ldsk[(nf * 16 + lrow) * 64 + ((lgrp) ^ (lrow & 7)) * 8]);
        const short8 kf1 = *reinterpret_cast<const short8*>(
            &ldsk[(nf * 16 + lrow) * 64 + ((4 + lgrp) ^ (lrow & 7)) * 8]);
#pragma unroll
        for (int qt = 0; qt < 4; ++qt) {
          floatx4 z = {};
          z = __builtin_amdgcn_mfma_f32_16x16x32_bf16(kf0, qf[qt][0], z, 0, 0, 0);
          z = __builtin_amdgcn_mfma_f32_16x16x32_bf16(kf1, qf[qt][1], z, 0, 0, 0);
          s[qt][nf] = z;
        }
      }
      __builtin_amdgcn_s_setprio(0);

      // ---- causal mask (wave's diag tile only)
      if (kb == lastkb) {
#pragma unroll
        for (int qt = 0; qt < 4; ++qt)
#pragma unroll
          for (int nf = 0; nf < 4; ++nf)
#pragma unroll
            for (int r = 0; r < 4; ++r) {
              const int kg_ = nf * 16 + lgrp * 4 + r;       // local k in tile
              const int qg_ = qt * 16 + lrow;               // local q in wave
              if (kg_ > qg_) s[qt][nf][r] = -1e30f;
            }
      }

      // ---- P = exp2(s): pack b64 -> per-wave per-qt LDS
#pragma unroll
      for (int qt = 0; qt < 4; ++qt) {
        float ls = 0.f;
#pragma unroll
        for (int nf = 0; nf < 4; ++nf) {
          const float p0 = __builtin_amdgcn_exp2f(s[qt][nf][0]);
          const float p1 = __builtin_amdgcn_exp2f(s[qt][nf][1]);
          const float p2 = __builtin_amdgcn_exp2f(s[qt][nf][2]);
          const float p3 = __builtin_amdgcn_exp2f(s[qt][nf][3]);
          ls += (p0 + p1) + (p2 + p3);
          short4v pk;
          pk.x = f2bf(p0); pk.y = f2bf(p1); pk.z = f2bf(p2); pk.w = f2bf(p3);
          const int c8 = (nf * 4 + lgrp) ^ ((lrow & 7) << 1);
          *reinterpret_cast<short4v*>(&lds_p[w][qt][lrow * 64 + c8 * 4]) = pk;
        }
        lsum[qt] += ls;
      }

      // ---- PV: A = P (per-wave LDS), B-frag = V^T rows; V read once per nf
      short8 pa[4][2];
      {
        const int c0 = ((lgrp) ^ (lrow & 7)) * 8;
        const int c1 = ((4 + lgrp) ^ (lrow & 7)) * 8;
#pragma unroll
        for (int qt = 0; qt < 4; ++qt) {
          pa[qt][0] = *reinterpret_cast<const short8*>(&lds_p[w][qt][lrow * 64 + c0]);
          pa[qt][1] = *reinterpret_cast<const short8*>(&lds_p[w][qt][lrow * 64 + c1]);
        }
      }
      __builtin_amdgcn_s_setprio(1);
#pragma unroll
      for (int nf = 0; nf < 4; ++nf) {
        const short8 vf0 = *reinterpret_cast<const short8*>(
            &ldsv[(nf * 16 + lrow) * 64 + ((lgrp) ^ (lrow & 7)) * 8]);
        const short8 vf1 = *reinterpret_cast<const short8*>(
            &ldsv[(nf * 16 + lrow) * 64 + ((4 + lgrp) ^ (lrow & 7)) * 8]);
#pragma unroll
        for (int qt = 0; qt < 4; ++qt) {
          oacc[qt][nf] = __builtin_amdgcn_mfma_f32_16x16x32_bf16(pa[qt][0], vf0, oacc[qt][nf], 0, 0, 0);
          oacc[qt][nf] = __builtin_amdgcn_mfma_f32_16x16x32_bf16(pa[qt][1], vf1, oacc[qt][nf], 0, 0, 0);
        }
      }
      __builtin_amdgcn_s_setprio(0);
    };

    stageK(kd0, kg); kg += 65536;
    stageV(vd0, vg); vg += 64;
    __syncthreads();

#pragma unroll 1
    for (int kb = 0; kb < nkb; kb += 2) {
      if (kb + 1 < nkb) { stageK(kd1, kg); kg += 65536; stageV(vd1, vg); vg += 64; }
      body(kb, lds_k[0], lds_v[0]);
      __syncthreads();
      if (kb + 1 >= nkb) break;
      if (kb + 2 < nkb) { stageK(kd0, kg); kg += 65536; stageV(vd0, vg); vg += 64; }
      body(kb + 1, lds_k[1], lds_v[1]);
      __syncthreads();
    }

    // ---- epilogue: reduce l per qt, write O rows qw + qt*16 + lgrp*4 + r
#pragma unroll
    for (int qt = 0; qt < 4; ++qt) {
      float lw = lsum[qt];
      lw += __shfl_xor(lw, 16, 64);
      lw += __shfl_xor(lw, 32, 64);
#pragma unroll
      for (int r = 0; r < 4; ++r) {
        const float linv = 1.0f / __shfl(lw, lgrp * 4 + r, 64);
        const int t = qw + qt * 16 + lgrp * 4 + r;
#pragma unroll
        for (int nf = 0; nf < 4; ++nf)
          O[base + (size_t)t * 1024 + nf * 16 + lrow] = f2bf(oacc[qt][nf][r] * linv);
      }
    }
  }
}

// ---------------- launcher ----------------
extern "C" void kernel_launch(void* const* d_in, const int* in_sizes, int n_in,
                              void* d_out, int out_size, void* d_ws, size_t ws_size,
                              hipStream_t stream) {
  const float* x  = (const float*)d_in[0];
  const float* Wq = (const float*)d_in[1];
  const float* Wk = (const float*)d_in[2];
  const float* Wv = (const float*)d_in[3];
  const float* Wo = (const float*)d_in[4];

  uint8_t* ws = (uint8_t*)d_ws;
  short* xb  = (short*)(ws + 0);           // 8192x1024 bf16  (16 MiB)
  short* wqb = (short*)(ws + 16777216);    // 4 x 1024x1024 bf16, contiguous
  short* wob = (short*)(ws + 23068672);
  short* Qb  = (short*)(ws + 25165824);    // 8192x1024 bf16
  short* Kb  = (short*)(ws + 41943040);
  short* Vt  = (short*)(ws + 58720256);    // [64 bh][64 d][2048 t] bf16
  short* Ob  = (short*)(ws + 75497472);
  if (ws_size < 92274688ull) return;  // fail loudly (output stays poisoned)

  const float qscale = 0.125f * LOG2E;     // fold head-scale + log2e into W_Q

  cvt_f32_bf16<<<8192, 256, 0, stream>>>(x, xb, 2097152, 1.0f);
  cvt_weights<<<dim3(1024, 4), 256, 0, stream>>>(Wq, Wk, Wv, Wo, wqb, qscale);

  gemm_qkv<<<256, 512, 0, stream>>>(xb, wqb, Qb, Kb, Vt);
  attn_fwd<<<512, 256, 0, stream>>>(Qb, Kb, Vt, Ob);
  gemm_out<<<256, 512, 0, stream>>>(Ob, wob, (float*)d_out);
}

// Round 18
// 152.956 us; speedup vs baseline: 1.1978x; 1.1978x over previous
//
#include <hip/hip_runtime.h>
#include <hip/hip_bf16.h>
#include <stdint.h>

// B=4, T=2048, D_MODEL=1024, H=16, hd=64
// Q/K token-major: [B*T, 1024], head h at cols h*64..h*64+63.
// V is stored TRANSPOSED: Vt[bh][d][t] = Vt[bh*131072 + d*2048 + t] (bf16).
// W_Q is pre-scaled by 0.125*log2(e) so softmax runs in log2 domain.

typedef __attribute__((ext_vector_type(8))) short short8;    // 8 x bf16 (4 VGPRs)
typedef __attribute__((ext_vector_type(4))) short short4v;
typedef __attribute__((ext_vector_type(4))) float floatx4;

#define LOG2E 1.4426950408889634f

__device__ __forceinline__ void gload_lds16(const void* g, void* l) {
  __builtin_amdgcn_global_load_lds(
      (const __attribute__((address_space(1))) void*)g,
      (__attribute__((address_space(3))) void*)l, 16, 0, 0);
}

__device__ __forceinline__ short f2bf(float f) {
  __hip_bfloat16 h = __float2bfloat16(f);
  return *reinterpret_cast<short*>(&h);
}

// ---------------- fp32 -> bf16 conversion ----------------
__global__ __launch_bounds__(256) void cvt_f32_bf16(const float* __restrict__ src,
                                                    short* __restrict__ dst, int n4,
                                                    float scale) {
  const int i = blockIdx.x * blockDim.x + threadIdx.x;
  if (i >= n4) return;
  const float4 v = reinterpret_cast<const float4*>(src)[i];
  short4v o;
  o.x = f2bf(v.x * scale); o.y = f2bf(v.y * scale);
  o.z = f2bf(v.z * scale); o.w = f2bf(v.w * scale);
  reinterpret_cast<short4v*>(dst)[i] = o;
}

// all 4 weights in one dispatch; dst buffers are contiguous (2 MiB apart).
__global__ __launch_bounds__(256) void cvt_weights(const float* __restrict__ wq,
                                                   const float* __restrict__ wk,
                                                   const float* __restrict__ wv,
                                                   const float* __restrict__ wo,
                                                   short* __restrict__ dst0,
                                                   float qscale) {
  const int y = blockIdx.y;
  const float* src = (y == 0) ? wq : (y == 1) ? wk : (y == 2) ? wv : wo;
  const float scale = (y == 0) ? qscale : 1.0f;
  short* dst = dst0 + (size_t)y * 1048576;
  const int i = blockIdx.x * blockDim.x + threadIdx.x;
  const float4 v = reinterpret_cast<const float4*>(src)[i];
  short4v o;
  o.x = f2bf(v.x * scale); o.y = f2bf(v.y * scale);
  o.z = f2bf(v.z * scale); o.w = f2bf(v.w * scale);
  reinterpret_cast<short4v*>(&dst[i * 4])[0] = o;
}

// ---- MERGED QKV GEMM (unchanged from round 16 — passing at 59.7us) ----
__global__ __launch_bounds__(512) void gemm_qkv(
    const short* __restrict__ xb, const short* __restrict__ wqkv,
    short* __restrict__ Qb, short* __restrict__ Kb, short* __restrict__ Vt) {
  __shared__ short lds_a[3][256 * 32];      // 48 KB
  __shared__ short lds_b[3][3 * 128 * 32];  // 72 KB : [buf][z][128r][32k]
  const int tid = threadIdx.x;
  const int lane = tid & 63;
  const int w = tid >> 6;                 // 0..7
  const int wm = w >> 1, wn = w & 1;      // 4M x 2N wave grid
  const int lrow = lane & 15, lgrp = lane >> 4;

  const int flat = blockIdx.x;            // 0..255
  const int n0 = (flat & 7) * 128;        // XCD-resident weight panel
  const int m0 = (flat >> 3) * 256;

  floatx4 acc[3][4][4] = {};

  const int srow = tid >> 2;              // 0..127
  const int scb = (tid & 3) ^ (srow & 3) ^ ((srow & 4) >> 1);
  const short* ag = xb + (size_t)(m0 + srow) * 1024 + scb * 8;
  const short* bg = wqkv + (size_t)(n0 + srow) * 1024 + scb * 8;

  auto stage5 = [&](short* la, short* lb) {
    gload_lds16(ag, la + tid * 8);
    gload_lds16(ag + 128 * 1024, la + (512 + tid) * 8);
    gload_lds16(bg,           lb + tid * 8);
    gload_lds16(bg + 1048576, lb + 4096 + tid * 8);
    gload_lds16(bg + 2097152, lb + 8192 + tid * 8);
    ag += 32; bg += 32;
  };

  const int slA = (lgrp ^ (lrow & 3) ^ ((lrow & 4) >> 1)) * 8;

  auto tile = [&](const short* la, const short* lb, short* na, short* nb, bool pf) {
    if (pf) stage5(na, nb);
    short8 af[4];
#pragma unroll
    for (int mf = 0; mf < 4; ++mf)
      af[mf] = *reinterpret_cast<const short8*>(
          &la[(wm * 64 + mf * 16 + lrow) * 32 + slA]);
#pragma unroll
    for (int z = 0; z < 3; ++z) {
      short8 bf[4];
#pragma unroll
      for (int nf = 0; nf < 4; ++nf)
        bf[nf] = *reinterpret_cast<const short8*>(
            &lb[z * 4096 + (wn * 64 + nf * 16 + lrow) * 32 + slA]);
      __builtin_amdgcn_s_setprio(1);
#pragma unroll
      for (int mf = 0; mf < 4; ++mf)
#pragma unroll
        for (int nf = 0; nf < 4; ++nf)
          acc[z][mf][nf] = __builtin_amdgcn_mfma_f32_16x16x32_bf16(
              af[mf], bf[nf], acc[z][mf][nf], 0, 0, 0);
      __builtin_amdgcn_s_setprio(0);
    }
  };

  auto tiletop = [&](int n) {
    __builtin_amdgcn_sched_barrier(0);
    if (n == 0)
      asm volatile("s_waitcnt vmcnt(0)" ::: "memory");
    else
      asm volatile("s_waitcnt vmcnt(5)" ::: "memory");
    __builtin_amdgcn_s_barrier();
    __builtin_amdgcn_sched_barrier(0);
  };

  stage5(lds_a[0], lds_b[0]);
  stage5(lds_a[1], lds_b[1]);

#pragma unroll 1
  for (int kt = 0; kt < 30; kt += 3) {
    tiletop(5); tile(lds_a[0], lds_b[0], lds_a[2], lds_b[2], true);
    tiletop(5); tile(lds_a[1], lds_b[1], lds_a[0], lds_b[0], true);
    tiletop(5); tile(lds_a[2], lds_b[2], lds_a[1], lds_b[1], true);
  }
  tiletop(5); tile(lds_a[0], lds_b[0], nullptr, nullptr, false);  // tile 30
  tiletop(0); tile(lds_a[1], lds_b[1], nullptr, nullptr, false);  // tile 31

#pragma unroll
  for (int z = 0; z < 3; ++z) {
#pragma unroll
    for (int mf = 0; mf < 4; ++mf) {
#pragma unroll
      for (int nf = 0; nf < 4; ++nf) {
        if (z == 2) {
          short4v pk;
#pragma unroll
          for (int r = 0; r < 4; ++r) pk[r] = f2bf(acc[z][mf][nf][r]);
          const int t0 = m0 + wm * 64 + mf * 16 + lgrp * 4;
          const int ch = n0 + wn * 64 + nf * 16 + lrow;
          const int bh = ((t0 >> 11) << 4) + (ch >> 6);
          *reinterpret_cast<short4v*>(
              &Vt[(size_t)bh * 131072 + (size_t)(ch & 63) * 2048 + (t0 & 2047)]) = pk;
        } else {
          short* C = (z == 0) ? Qb : Kb;
#pragma unroll
          for (int r = 0; r < 4; ++r) {
            const int grow = m0 + wm * 64 + mf * 16 + lgrp * 4 + r;
            const int gcol = n0 + wn * 64 + nf * 16 + lrow;
            C[(size_t)grow * 1024 + gcol] = f2bf(acc[z][mf][nf][r]);
          }
        }
      }
    }
  }
}

// ---- single-output GEMM (O-projection), r14 structure (unchanged, passing) ----
template <int MODE>
__device__ __forceinline__ void gemm256_body(const short* __restrict__ A,
                                             const short* __restrict__ B,
                                             void* __restrict__ Cout,
                                             int m0, int n0,
                                             short* __restrict__ la0,
                                             short* __restrict__ la1,
                                             short* __restrict__ la2,
                                             short* __restrict__ lb0,
                                             short* __restrict__ lb1,
                                             short* __restrict__ lb2) {
  const int tid = threadIdx.x;
  const int lane = tid & 63;
  const int w = tid >> 6;
  const int wm = w >> 1, wn = w & 1;
  const int lrow = lane & 15, lgrp = lane >> 4;

  floatx4 acc[4][4] = {};

  const int srow = tid >> 2;
  const int scb = (tid & 3) ^ (srow & 3) ^ ((srow & 4) >> 1);
  const short* ag = A + (size_t)(m0 + srow) * 1024 + scb * 8;
  const short* bg = B + (size_t)(n0 + srow) * 1024 + scb * 8;

  auto stage3 = [&](short* la, short* lb) {
    gload_lds16(ag, la + tid * 8);
    gload_lds16(ag + 128 * 1024, la + (512 + tid) * 8);
    gload_lds16(bg, lb + tid * 8);
    ag += 32; bg += 32;
  };

  const int slA = (lgrp ^ (lrow & 3) ^ ((lrow & 4) >> 1)) * 8;

  auto tile = [&](const short* la, const short* lb, short* na, short* nb, bool pf) {
    if (pf) stage3(na, nb);
    short8 af[4], bf[4];
#pragma unroll
    for (int mf = 0; mf < 4; ++mf) {
      const int row = wm * 64 + mf * 16 + lrow;
      af[mf] = *reinterpret_cast<const short8*>(&la[row * 32 + slA]);
    }
#pragma unroll
    for (int nf = 0; nf < 4; ++nf) {
      const int row = wn * 64 + nf * 16 + lrow;
      bf[nf] = *reinterpret_cast<const short8*>(&lb[row * 32 + slA]);
    }
    __builtin_amdgcn_s_setprio(1);
#pragma unroll
    for (int mf = 0; mf < 4; ++mf)
#pragma unroll
      for (int nf = 0; nf < 4; ++nf)
        acc[mf][nf] = __builtin_amdgcn_mfma_f32_16x16x32_bf16(af[mf], bf[nf], acc[mf][nf], 0, 0, 0);
    __builtin_amdgcn_s_setprio(0);
  };

  auto tiletop = [&](int n) {
    __builtin_amdgcn_sched_barrier(0);
    if (n == 0)
      asm volatile("s_waitcnt vmcnt(0)" ::: "memory");
    else
      asm volatile("s_waitcnt vmcnt(3)" ::: "memory");
    __builtin_amdgcn_s_barrier();
    __builtin_amdgcn_sched_barrier(0);
  };

  stage3(la0, lb0);
  stage3(la1, lb1);

#pragma unroll 1
  for (int kt = 0; kt < 30; kt += 3) {
    tiletop(3); tile(la0, lb0, la2, lb2, true);
    tiletop(3); tile(la1, lb1, la0, lb0, true);
    tiletop(3); tile(la2, lb2, la1, lb1, true);
  }
  tiletop(3); tile(la0, lb0, nullptr, nullptr, false);
  tiletop(0); tile(la1, lb1, nullptr, nullptr, false);

#pragma unroll
  for (int mf = 0; mf < 4; ++mf) {
#pragma unroll
    for (int nf = 0; nf < 4; ++nf) {
#pragma unroll
      for (int r = 0; r < 4; ++r) {
        const int grow = m0 + wm * 64 + mf * 16 + lgrp * 4 + r;
        const int gcol = n0 + wn * 64 + nf * 16 + lrow;
        if (MODE == 1)
          reinterpret_cast<short*>(Cout)[(size_t)grow * 1024 + gcol] = f2bf(acc[mf][nf][r]);
        else
          reinterpret_cast<float*>(Cout)[(size_t)grow * 1024 + gcol] = acc[mf][nf][r];
      }
    }
  }
}

__global__ __launch_bounds__(512) void gemm_out(const short* __restrict__ Ob,
                                                const short* __restrict__ wo,
                                                float* __restrict__ out) {
  __shared__ short lds_a[3][256 * 32];
  __shared__ short lds_b[3][128 * 32];
  const int flat = blockIdx.x;
  const int xcd = flat & 7, rest = flat >> 3;
  const int nblk = rest & 7, pg = rest >> 3;
  const int panel = pg * 8 + xcd;
  gemm256_body<0>(Ob, wo, out, panel * 256, nblk * 128,
                  lds_a[0], lds_a[1], lds_a[2], lds_b[0], lds_b[1], lds_b[2]);
}

// ---------------- flash attention (causal), bf16 in/out ----------------
// 512 threads = 8 waves; wave owns TWO 16-row q-tiles (32 q rows) — the r15
// traffic-amortized body verbatim, but 8 waves/block: block covers 256 q rows,
// LDS 64KB -> 2 blocks/CU = 16 waves/CU (double r15's latency hiding).
// Grid 256: bh = flat & 63 (XCD locality), p = flat >> 6 (0..3); block p
// processes chunk (7-p) then chunk p -> exactly 36 KV-tile iterations/block.
// Per-wave diag lastkb = 4qc + (w>>1) (early-return guard; barriers in caller).
// Static-offset softmax: P = exp2(s) (log2 domain, scale cancels in /l).
__global__ __launch_bounds__(512, 4) void attn_fwd(const short* __restrict__ Q,
                                                   const short* __restrict__ K,
                                                   const short* __restrict__ Vt,
                                                   short* __restrict__ O) {
  __shared__ short lds_k[2][64 * 64];      // 16 KB
  __shared__ short lds_v[2][64 * 64];      // 16 KB : [d][k] swizzled
  __shared__ short lds_p[8][2][16 * 64];   // 32 KB : [wave][qt][16q][64k] swizzled

  const int tid = threadIdx.x;
  const int lane = tid & 63;
  const int w = tid >> 6;                // 0..7
  const int lrow = lane & 15, lgrp = lane >> 4;
  const int flat = blockIdx.x;
  const int bh = flat & 63;              // XCD-locality: same bh -> same XCD
  const int p = flat >> 6;               // 0..3 -> chunk pair (7-p, p)
  const int b = bh >> 4, h = bh & 15;

  const size_t base = (size_t)b * 2048 * 1024 + h * 64;
  const size_t vbase = (size_t)bh * 131072;

  // staging: K tile 64x64 = 512 16B-chunks, 1/thread; V same via Vt rows.
  const int srow = tid >> 3;                         // 0..63
  const int scb = (tid & 7) ^ (srow & 7);
  const size_t koff = (size_t)srow * 1024 + scb * 8;
  const size_t voff = (size_t)srow * 2048 + scb * 8;
  short* const kd0 = &lds_k[0][tid * 8];
  short* const kd1 = &lds_k[1][tid * 8];
  short* const vd0 = &lds_v[0][tid * 8];
  short* const vd1 = &lds_v[1][tid * 8];

  auto stageK = [&](short* ldst, const short* gsrc) { gload_lds16(gsrc, ldst); };
  auto stageV = [&](short* ldst, const short* gsrc) { gload_lds16(gsrc, ldst); };

#pragma unroll 1
  for (int pass = 0; pass < 2; ++pass) {
    const int qc = pass == 0 ? (7 - p) : p;    // 256-row q-chunk index
    const int qw = qc * 256 + w * 32;          // wave's first q row
    const int lastkb = 4 * qc + (w >> 1);      // wave's diag KV tile
    const int nkb = 4 * qc + 4;                // block KV-tile count

    // Q B-frags: qf[qt][half] = Q[qw + qt*16 + lrow][half*32 + lgrp*8 .. +8]
    short8 qf[2][2];
#pragma unroll
    for (int qt = 0; qt < 2; ++qt) {
      const short* qp = Q + base + (size_t)(qw + qt * 16 + lrow) * 1024 + lgrp * 8;
      qf[qt][0] = *reinterpret_cast<const short8*>(qp);
      qf[qt][1] = *reinterpret_cast<const short8*>(qp + 32);
    }

    floatx4 oacc[2][4] = {};
    float lsum0 = 0.f, lsum1 = 0.f;

    const short* kg = K + base + koff;
    const short* vg = Vt + vbase + voff;

    auto body = [&](int kb, const short* __restrict__ ldsk,
                    const short* __restrict__ ldsv) {
      if (kb > lastkb) return;   // wave done (barriers handled by caller)
      floatx4 s[2][4];
      __builtin_amdgcn_s_setprio(1);
#pragma unroll
      for (int nf = 0; nf < 4; ++nf) {
        const short8 kf0 = *reinterpret_cast<const short8*>(
            &ldsk[(nf * 16 + lrow) * 64 + ((lgrp) ^ (lrow & 7)) * 8]);
        const short8 kf1 = *reinterpret_cast<const short8*>(
            &ldsk[(nf * 16 + lrow) * 64 + ((4 + lgrp) ^ (lrow & 7)) * 8]);
#pragma unroll
        for (int qt = 0; qt < 2; ++qt) {
          floatx4 z = {};
          z = __builtin_amdgcn_mfma_f32_16x16x32_bf16(kf0, qf[qt][0], z, 0, 0, 0);
          z = __builtin_amdgcn_mfma_f32_16x16x32_bf16(kf1, qf[qt][1], z, 0, 0, 0);
          s[qt][nf] = z;
        }
      }
      __builtin_amdgcn_s_setprio(0);

      // causal mask (wave's diag tile only); local k vs wave-local q
      if (kb == lastkb) {
        const int qloc = (w & 1) * 32;   // wave's q offset within its diag tile
#pragma unroll
        for (int qt = 0; qt < 2; ++qt)
#pragma unroll
          for (int nf = 0; nf < 4; ++nf)
#pragma unroll
            for (int r = 0; r < 4; ++r) {
              const int kg_ = nf * 16 + lgrp * 4 + r;
              const int qg_ = qloc + qt * 16 + lrow;
              if (kg_ > qg_) s[qt][nf][r] = -1e30f;
            }
      }

#pragma unroll
      for (int qt = 0; qt < 2; ++qt) {
        float ls = 0.f;
#pragma unroll
        for (int nf = 0; nf < 4; ++nf) {
          const float p0 = __builtin_amdgcn_exp2f(s[qt][nf][0]);
          const float p1 = __builtin_amdgcn_exp2f(s[qt][nf][1]);
          const float p2 = __builtin_amdgcn_exp2f(s[qt][nf][2]);
          const float p3 = __builtin_amdgcn_exp2f(s[qt][nf][3]);
          ls += (p0 + p1) + (p2 + p3);
          short4v pk;
          pk.x = f2bf(p0); pk.y = f2bf(p1); pk.z = f2bf(p2); pk.w = f2bf(p3);
          const int c8 = (nf * 4 + lgrp) ^ ((lrow & 7) << 1);
          *reinterpret_cast<short4v*>(&lds_p[w][qt][lrow * 64 + c8 * 4]) = pk;
        }
        if (qt == 0) lsum0 += ls; else lsum1 += ls;
      }

      short8 pa[2][2];
      {
        const int c0 = ((lgrp) ^ (lrow & 7)) * 8;
        const int c1 = ((4 + lgrp) ^ (lrow & 7)) * 8;
#pragma unroll
        for (int qt = 0; qt < 2; ++qt) {
          pa[qt][0] = *reinterpret_cast<const short8*>(&lds_p[w][qt][lrow * 64 + c0]);
          pa[qt][1] = *reinterpret_cast<const short8*>(&lds_p[w][qt][lrow * 64 + c1]);
        }
      }
      __builtin_amdgcn_s_setprio(1);
#pragma unroll
      for (int nf = 0; nf < 4; ++nf) {
        const short8 vf0 = *reinterpret_cast<const short8*>(
            &ldsv[(nf * 16 + lrow) * 64 + ((lgrp) ^ (lrow & 7)) * 8]);
        const short8 vf1 = *reinterpret_cast<const short8*>(
            &ldsv[(nf * 16 + lrow) * 64 + ((4 + lgrp) ^ (lrow & 7)) * 8]);
#pragma unroll
        for (int qt = 0; qt < 2; ++qt) {
          oacc[qt][nf] = __builtin_amdgcn_mfma_f32_16x16x32_bf16(pa[qt][0], vf0, oacc[qt][nf], 0, 0, 0);
          oacc[qt][nf] = __builtin_amdgcn_mfma_f32_16x16x32_bf16(pa[qt][1], vf1, oacc[qt][nf], 0, 0, 0);
        }
      }
      __builtin_amdgcn_s_setprio(0);
    };

    stageK(kd0, kg); kg += 65536;
    stageV(vd0, vg); vg += 64;
    __syncthreads();

#pragma unroll 1
    for (int kb = 0; kb < nkb; kb += 2) {
      if (kb + 1 < nkb) { stageK(kd1, kg); kg += 65536; stageV(vd1, vg); vg += 64; }
      body(kb, lds_k[0], lds_v[0]);
      __syncthreads();
      if (kb + 1 >= nkb) break;
      if (kb + 2 < nkb) { stageK(kd0, kg); kg += 65536; stageV(vd0, vg); vg += 64; }
      body(kb + 1, lds_k[1], lds_v[1]);
      __syncthreads();
    }

    // epilogue: reduce l per qt, write O rows qw + qt*16 + lgrp*4 + r
    lsum0 += __shfl_xor(lsum0, 16, 64);
    lsum0 += __shfl_xor(lsum0, 32, 64);
    lsum1 += __shfl_xor(lsum1, 16, 64);
    lsum1 += __shfl_xor(lsum1, 32, 64);
#pragma unroll
    for (int qt = 0; qt < 2; ++qt) {
      const float lw = qt == 0 ? lsum0 : lsum1;
#pragma unroll
      for (int r = 0; r < 4; ++r) {
        const float linv = 1.0f / __shfl(lw, lgrp * 4 + r, 64);
        const int t = qw + qt * 16 + lgrp * 4 + r;
#pragma unroll
        for (int nf = 0; nf < 4; ++nf)
          O[base + (size_t)t * 1024 + nf * 16 + lrow] = f2bf(oacc[qt][nf][r] * linv);
      }
    }
  }
}

// ---------------- launcher ----------------
extern "C" void kernel_launch(void* const* d_in, const int* in_sizes, int n_in,
                              void* d_out, int out_size, void* d_ws, size_t ws_size,
                              hipStream_t stream) {
  const float* x  = (const float*)d_in[0];
  const float* Wq = (const float*)d_in[1];
  const float* Wk = (const float*)d_in[2];
  const float* Wv = (const float*)d_in[3];
  const float* Wo = (const float*)d_in[4];

  uint8_t* ws = (uint8_t*)d_ws;
  short* xb  = (short*)(ws + 0);           // 8192x1024 bf16  (16 MiB)
  short* wqb = (short*)(ws + 16777216);    // 4 x 1024x1024 bf16, contiguous
  short* wob = (short*)(ws + 23068672);
  short* Qb  = (short*)(ws + 25165824);    // 8192x1024 bf16
  short* Kb  = (short*)(ws + 41943040);
  short* Vt  = (short*)(ws + 58720256);    // [64 bh][64 d][2048 t] bf16
  short* Ob  = (short*)(ws + 75497472);
  if (ws_size < 92274688ull) return;  // fail loudly (output stays poisoned)

  const float qscale = 0.125f * LOG2E;     // fold head-scale + log2e into W_Q

  cvt_f32_bf16<<<8192, 256, 0, stream>>>(x, xb, 2097152, 1.0f);
  cvt_weights<<<dim3(1024, 4), 256, 0, stream>>>(Wq, Wk, Wv, Wo, wqb, qscale);

  gemm_qkv<<<256, 512, 0, stream>>>(xb, wqb, Qb, Kb, Vt);
  attn_fwd<<<256, 512, 0, stream>>>(Qb, Kb, Vt, Ob);
  gemm_out<<<256, 512, 0, stream>>>(Ob, wob, (float*)d_out);
}

// Round 19
// 147.826 us; speedup vs baseline: 1.2393x; 1.0347x over previous
//
#include <hip/hip_runtime.h>
#include <hip/hip_bf16.h>
#include <stdint.h>

// B=4, T=2048, D_MODEL=1024, H=16, hd=64
// Q/K token-major: [B*T, 1024], head h at cols h*64..h*64+63.
// V is stored TRANSPOSED: Vt[bh][d][t] = Vt[bh*131072 + d*2048 + t] (bf16).
// W_Q is pre-scaled by 0.125*log2(e) so softmax runs in log2 domain.

typedef __attribute__((ext_vector_type(8))) short short8;    // 8 x bf16 (4 VGPRs)
typedef __attribute__((ext_vector_type(4))) short short4v;
typedef __attribute__((ext_vector_type(4))) float floatx4;

#define LOG2E 1.4426950408889634f

__device__ __forceinline__ void gload_lds16(const void* g, void* l) {
  __builtin_amdgcn_global_load_lds(
      (const __attribute__((address_space(1))) void*)g,
      (__attribute__((address_space(3))) void*)l, 16, 0, 0);
}

__device__ __forceinline__ short f2bf(float f) {
  __hip_bfloat16 h = __float2bfloat16(f);
  return *reinterpret_cast<short*>(&h);
}

// ---------------- fp32 -> bf16 conversion ----------------
__global__ __launch_bounds__(256) void cvt_f32_bf16(const float* __restrict__ src,
                                                    short* __restrict__ dst, int n4,
                                                    float scale) {
  const int i = blockIdx.x * blockDim.x + threadIdx.x;
  if (i >= n4) return;
  const float4 v = reinterpret_cast<const float4*>(src)[i];
  short4v o;
  o.x = f2bf(v.x * scale); o.y = f2bf(v.y * scale);
  o.z = f2bf(v.z * scale); o.w = f2bf(v.w * scale);
  reinterpret_cast<short4v*>(dst)[i] = o;
}

// all 4 weights in one dispatch; dst buffers are contiguous (2 MiB apart).
__global__ __launch_bounds__(256) void cvt_weights(const float* __restrict__ wq,
                                                   const float* __restrict__ wk,
                                                   const float* __restrict__ wv,
                                                   const float* __restrict__ wo,
                                                   short* __restrict__ dst0,
                                                   float qscale) {
  const int y = blockIdx.y;
  const float* src = (y == 0) ? wq : (y == 1) ? wk : (y == 2) ? wv : wo;
  const float scale = (y == 0) ? qscale : 1.0f;
  short* dst = dst0 + (size_t)y * 1048576;
  const int i = blockIdx.x * blockDim.x + threadIdx.x;
  const float4 v = reinterpret_cast<const float4*>(src)[i];
  short4v o;
  o.x = f2bf(v.x * scale); o.y = f2bf(v.y * scale);
  o.z = f2bf(v.z * scale); o.w = f2bf(v.w * scale);
  reinterpret_cast<short4v*>(&dst[i * 4])[0] = o;
}

// ---- MERGED QKV GEMM (unchanged from round 16 — passing at 59.7us) ----
__global__ __launch_bounds__(512) void gemm_qkv(
    const short* __restrict__ xb, const short* __restrict__ wqkv,
    short* __restrict__ Qb, short* __restrict__ Kb, short* __restrict__ Vt) {
  __shared__ short lds_a[3][256 * 32];      // 48 KB
  __shared__ short lds_b[3][3 * 128 * 32];  // 72 KB : [buf][z][128r][32k]
  const int tid = threadIdx.x;
  const int lane = tid & 63;
  const int w = tid >> 6;                 // 0..7
  const int wm = w >> 1, wn = w & 1;      // 4M x 2N wave grid
  const int lrow = lane & 15, lgrp = lane >> 4;

  const int flat = blockIdx.x;            // 0..255
  const int n0 = (flat & 7) * 128;        // XCD-resident weight panel
  const int m0 = (flat >> 3) * 256;

  floatx4 acc[3][4][4] = {};

  const int srow = tid >> 2;              // 0..127
  const int scb = (tid & 3) ^ (srow & 3) ^ ((srow & 4) >> 1);
  const short* ag = xb + (size_t)(m0 + srow) * 1024 + scb * 8;
  const short* bg = wqkv + (size_t)(n0 + srow) * 1024 + scb * 8;

  auto stage5 = [&](short* la, short* lb) {
    gload_lds16(ag, la + tid * 8);
    gload_lds16(ag + 128 * 1024, la + (512 + tid) * 8);
    gload_lds16(bg,           lb + tid * 8);
    gload_lds16(bg + 1048576, lb + 4096 + tid * 8);
    gload_lds16(bg + 2097152, lb + 8192 + tid * 8);
    ag += 32; bg += 32;
  };

  const int slA = (lgrp ^ (lrow & 3) ^ ((lrow & 4) >> 1)) * 8;

  auto tile = [&](const short* la, const short* lb, short* na, short* nb, bool pf) {
    if (pf) stage5(na, nb);
    short8 af[4];
#pragma unroll
    for (int mf = 0; mf < 4; ++mf)
      af[mf] = *reinterpret_cast<const short8*>(
          &la[(wm * 64 + mf * 16 + lrow) * 32 + slA]);
#pragma unroll
    for (int z = 0; z < 3; ++z) {
      short8 bf[4];
#pragma unroll
      for (int nf = 0; nf < 4; ++nf)
        bf[nf] = *reinterpret_cast<const short8*>(
            &lb[z * 4096 + (wn * 64 + nf * 16 + lrow) * 32 + slA]);
      __builtin_amdgcn_s_setprio(1);
#pragma unroll
      for (int mf = 0; mf < 4; ++mf)
#pragma unroll
        for (int nf = 0; nf < 4; ++nf)
          acc[z][mf][nf] = __builtin_amdgcn_mfma_f32_16x16x32_bf16(
              af[mf], bf[nf], acc[z][mf][nf], 0, 0, 0);
      __builtin_amdgcn_s_setprio(0);
    }
  };

  auto tiletop = [&](int n) {
    __builtin_amdgcn_sched_barrier(0);
    if (n == 0)
      asm volatile("s_waitcnt vmcnt(0)" ::: "memory");
    else
      asm volatile("s_waitcnt vmcnt(5)" ::: "memory");
    __builtin_amdgcn_s_barrier();
    __builtin_amdgcn_sched_barrier(0);
  };

  stage5(lds_a[0], lds_b[0]);
  stage5(lds_a[1], lds_b[1]);

#pragma unroll 1
  for (int kt = 0; kt < 30; kt += 3) {
    tiletop(5); tile(lds_a[0], lds_b[0], lds_a[2], lds_b[2], true);
    tiletop(5); tile(lds_a[1], lds_b[1], lds_a[0], lds_b[0], true);
    tiletop(5); tile(lds_a[2], lds_b[2], lds_a[1], lds_b[1], true);
  }
  tiletop(5); tile(lds_a[0], lds_b[0], nullptr, nullptr, false);  // tile 30
  tiletop(0); tile(lds_a[1], lds_b[1], nullptr, nullptr, false);  // tile 31

#pragma unroll
  for (int z = 0; z < 3; ++z) {
#pragma unroll
    for (int mf = 0; mf < 4; ++mf) {
#pragma unroll
      for (int nf = 0; nf < 4; ++nf) {
        if (z == 2) {
          short4v pk;
#pragma unroll
          for (int r = 0; r < 4; ++r) pk[r] = f2bf(acc[z][mf][nf][r]);
          const int t0 = m0 + wm * 64 + mf * 16 + lgrp * 4;
          const int ch = n0 + wn * 64 + nf * 16 + lrow;
          const int bh = ((t0 >> 11) << 4) + (ch >> 6);
          *reinterpret_cast<short4v*>(
              &Vt[(size_t)bh * 131072 + (size_t)(ch & 63) * 2048 + (t0 & 2047)]) = pk;
        } else {
          short* C = (z == 0) ? Qb : Kb;
#pragma unroll
          for (int r = 0; r < 4; ++r) {
            const int grow = m0 + wm * 64 + mf * 16 + lgrp * 4 + r;
            const int gcol = n0 + wn * 64 + nf * 16 + lrow;
            C[(size_t)grow * 1024 + gcol] = f2bf(acc[z][mf][nf][r]);
          }
        }
      }
    }
  }
}

// ---- single-output GEMM (O-projection), r14 structure (unchanged, passing) ----
template <int MODE>
__device__ __forceinline__ void gemm256_body(const short* __restrict__ A,
                                             const short* __restrict__ B,
                                             void* __restrict__ Cout,
                                             int m0, int n0,
                                             short* __restrict__ la0,
                                             short* __restrict__ la1,
                                             short* __restrict__ la2,
                                             short* __restrict__ lb0,
                                             short* __restrict__ lb1,
                                             short* __restrict__ lb2) {
  const int tid = threadIdx.x;
  const int lane = tid & 63;
  const int w = tid >> 6;
  const int wm = w >> 1, wn = w & 1;
  const int lrow = lane & 15, lgrp = lane >> 4;

  floatx4 acc[4][4] = {};

  const int srow = tid >> 2;
  const int scb = (tid & 3) ^ (srow & 3) ^ ((srow & 4) >> 1);
  const short* ag = A + (size_t)(m0 + srow) * 1024 + scb * 8;
  const short* bg = B + (size_t)(n0 + srow) * 1024 + scb * 8;

  auto stage3 = [&](short* la, short* lb) {
    gload_lds16(ag, la + tid * 8);
    gload_lds16(ag + 128 * 1024, la + (512 + tid) * 8);
    gload_lds16(bg, lb + tid * 8);
    ag += 32; bg += 32;
  };

  const int slA = (lgrp ^ (lrow & 3) ^ ((lrow & 4) >> 1)) * 8;

  auto tile = [&](const short* la, const short* lb, short* na, short* nb, bool pf) {
    if (pf) stage3(na, nb);
    short8 af[4], bf[4];
#pragma unroll
    for (int mf = 0; mf < 4; ++mf) {
      const int row = wm * 64 + mf * 16 + lrow;
      af[mf] = *reinterpret_cast<const short8*>(&la[row * 32 + slA]);
    }
#pragma unroll
    for (int nf = 0; nf < 4; ++nf) {
      const int row = wn * 64 + nf * 16 + lrow;
      bf[nf] = *reinterpret_cast<const short8*>(&lb[row * 32 + slA]);
    }
    __builtin_amdgcn_s_setprio(1);
#pragma unroll
    for (int mf = 0; mf < 4; ++mf)
#pragma unroll
      for (int nf = 0; nf < 4; ++nf)
        acc[mf][nf] = __builtin_amdgcn_mfma_f32_16x16x32_bf16(af[mf], bf[nf], acc[mf][nf], 0, 0, 0);
    __builtin_amdgcn_s_setprio(0);
  };

  auto tiletop = [&](int n) {
    __builtin_amdgcn_sched_barrier(0);
    if (n == 0)
      asm volatile("s_waitcnt vmcnt(0)" ::: "memory");
    else
      asm volatile("s_waitcnt vmcnt(3)" ::: "memory");
    __builtin_amdgcn_s_barrier();
    __builtin_amdgcn_sched_barrier(0);
  };

  stage3(la0, lb0);
  stage3(la1, lb1);

#pragma unroll 1
  for (int kt = 0; kt < 30; kt += 3) {
    tiletop(3); tile(la0, lb0, la2, lb2, true);
    tiletop(3); tile(la1, lb1, la0, lb0, true);
    tiletop(3); tile(la2, lb2, la1, lb1, true);
  }
  tiletop(3); tile(la0, lb0, nullptr, nullptr, false);
  tiletop(0); tile(la1, lb1, nullptr, nullptr, false);

#pragma unroll
  for (int mf = 0; mf < 4; ++mf) {
#pragma unroll
    for (int nf = 0; nf < 4; ++nf) {
#pragma unroll
      for (int r = 0; r < 4; ++r) {
        const int grow = m0 + wm * 64 + mf * 16 + lgrp * 4 + r;
        const int gcol = n0 + wn * 64 + nf * 16 + lrow;
        if (MODE == 1)
          reinterpret_cast<short*>(Cout)[(size_t)grow * 1024 + gcol] = f2bf(acc[mf][nf][r]);
        else
          reinterpret_cast<float*>(Cout)[(size_t)grow * 1024 + gcol] = acc[mf][nf][r];
      }
    }
  }
}

__global__ __launch_bounds__(512) void gemm_out(const short* __restrict__ Ob,
                                                const short* __restrict__ wo,
                                                float* __restrict__ out) {
  __shared__ short lds_a[3][256 * 32];
  __shared__ short lds_b[3][128 * 32];
  const int flat = blockIdx.x;
  const int xcd = flat & 7, rest = flat >> 3;
  const int nblk = rest & 7, pg = rest >> 3;
  const int panel = pg * 8 + xcd;
  gemm256_body<0>(Ob, wo, out, panel * 256, nblk * 128,
                  lds_a[0], lds_a[1], lds_a[2], lds_b[0], lds_b[1], lds_b[2]);
}

// ---------------- flash attention (causal), bf16 in/out ----------------
// 256 threads = 4 waves; wave owns TWO 16-row q-tiles (32 q rows) — r15 body.
// ONE 128-row chunk per block; grid 1024; LDS 40KB -> 4 blocks/CU = 16 waves/CU.
// P transpose medium is a SINGLE 2KB buffer per wave, reused across qt:
// {write P0; read pa0; write P1; read pa1} (per-wave, in-order DS) -> pa in
// regs for PV, V-frags still read once per nf (amortized over both qt).
// Balance: p = flat>>6, qc = 4*((p&3 + p>>2)&3) + (p>>2) — Latin-square decode:
// each CU's 4 residents (p, p+4, p+8, p+12) have qc summing to exactly 30.
// bh = flat & 63 keeps XCD-L2 locality. lastkb = 2qc + (w>>1).
__global__ __launch_bounds__(256, 4) void attn_fwd(const short* __restrict__ Q,
                                                   const short* __restrict__ K,
                                                   const short* __restrict__ Vt,
                                                   short* __restrict__ O) {
  __shared__ short lds_k[2][64 * 64];    // 16 KB
  __shared__ short lds_v[2][64 * 64];    // 16 KB : [d][k] swizzled
  __shared__ short lds_p[4][16 * 64];    //  8 KB : [wave][16q][64k] swizzled (reused per qt)

  const int tid = threadIdx.x;
  const int lane = tid & 63;
  const int w = tid >> 6;                // 0..3
  const int lrow = lane & 15, lgrp = lane >> 4;
  const int flat = blockIdx.x;
  const int bh = flat & 63;              // XCD-locality: same bh -> same XCD
  const int p = flat >> 6;               // 0..15
  const int qc = 4 * (((p & 3) + (p >> 2)) & 3) + (p >> 2);  // Latin-square chunk
  const int b = bh >> 4, h = bh & 15;

  const size_t base = (size_t)b * 2048 * 1024 + h * 64;
  const size_t vbase = (size_t)bh * 131072;

  const int srow = tid >> 3;                         // 0..31
  const int scb = (tid & 7) ^ (srow & 7);
  const size_t koff = (size_t)srow * 1024 + scb * 8;
  const size_t voff = (size_t)srow * 2048 + scb * 8;
  short* const kd0 = &lds_k[0][tid * 8];
  short* const kd1 = &lds_k[1][tid * 8];
  short* const vd0 = &lds_v[0][tid * 8];
  short* const vd1 = &lds_v[1][tid * 8];

  auto stageK = [&](short* ldst, const short* gsrc) {
    gload_lds16(gsrc, ldst);
    gload_lds16(gsrc + 32 * 1024, ldst + 2048);
  };
  auto stageV = [&](short* ldst, const short* gsrc) {
    gload_lds16(gsrc, ldst);
    gload_lds16(gsrc + 32 * 2048, ldst + 2048);
  };

  const int qw = qc * 128 + w * 32;          // wave's first q row
  const int lastkb = 2 * qc + (w >> 1);      // wave's diag KV tile
  const int nkb = 2 * qc + 2;                // block KV-tile count

  // Q B-frags: qf[qt][half] = Q[qw + qt*16 + lrow][half*32 + lgrp*8 .. +8]
  short8 qf[2][2];
#pragma unroll
  for (int qt = 0; qt < 2; ++qt) {
    const short* qp = Q + base + (size_t)(qw + qt * 16 + lrow) * 1024 + lgrp * 8;
    qf[qt][0] = *reinterpret_cast<const short8*>(qp);
    qf[qt][1] = *reinterpret_cast<const short8*>(qp + 32);
  }

  floatx4 oacc[2][4] = {};
  float lsum0 = 0.f, lsum1 = 0.f;

  const short* kg = K + base + koff;
  const short* vg = Vt + vbase + voff;

  auto body = [&](int kb, const short* __restrict__ ldsk,
                  const short* __restrict__ ldsv) {
    if (kb > lastkb) return;   // wave done (barriers handled by caller)
    floatx4 s[2][4];
    __builtin_amdgcn_s_setprio(1);
#pragma unroll
    for (int nf = 0; nf < 4; ++nf) {
      const short8 kf0 = *reinterpret_cast<const short8*>(
          &ldsk[(nf * 16 + lrow) * 64 + ((lgrp) ^ (lrow & 7)) * 8]);
      const short8 kf1 = *reinterpret_cast<const short8*>(
          &ldsk[(nf * 16 + lrow) * 64 + ((4 + lgrp) ^ (lrow & 7)) * 8]);
#pragma unroll
      for (int qt = 0; qt < 2; ++qt) {
        floatx4 z = {};
        z = __builtin_amdgcn_mfma_f32_16x16x32_bf16(kf0, qf[qt][0], z, 0, 0, 0);
        z = __builtin_amdgcn_mfma_f32_16x16x32_bf16(kf1, qf[qt][1], z, 0, 0, 0);
        s[qt][nf] = z;
      }
    }
    __builtin_amdgcn_s_setprio(0);

    // causal mask (wave's diag tile only), global coordinates
    if (kb == lastkb) {
#pragma unroll
      for (int qt = 0; qt < 2; ++qt)
#pragma unroll
        for (int nf = 0; nf < 4; ++nf)
#pragma unroll
          for (int r = 0; r < 4; ++r) {
            const int kg_ = kb * 64 + nf * 16 + lgrp * 4 + r;
            const int qg_ = qw + qt * 16 + lrow;
            if (kg_ > qg_) s[qt][nf][r] = -1e30f;
          }
    }

    // P = exp2(s): per-qt {write P -> read pa} through the SAME per-wave buffer
    short8 pa[2][2];
    const int c8w = (lgrp) /*base*/;
#pragma unroll
    for (int qt = 0; qt < 2; ++qt) {
      float ls = 0.f;
#pragma unroll
      for (int nf = 0; nf < 4; ++nf) {
        const float p0 = __builtin_amdgcn_exp2f(s[qt][nf][0]);
        const float p1 = __builtin_amdgcn_exp2f(s[qt][nf][1]);
        const float p2 = __builtin_amdgcn_exp2f(s[qt][nf][2]);
        const float p3 = __builtin_amdgcn_exp2f(s[qt][nf][3]);
        ls += (p0 + p1) + (p2 + p3);
        short4v pk;
        pk.x = f2bf(p0); pk.y = f2bf(p1); pk.z = f2bf(p2); pk.w = f2bf(p3);
        const int c8 = (nf * 4 + lgrp) ^ ((lrow & 7) << 1);
        *reinterpret_cast<short4v*>(&lds_p[w][lrow * 64 + c8 * 4]) = pk;
      }
      if (qt == 0) lsum0 += ls; else lsum1 += ls;
      const int c0 = ((lgrp) ^ (lrow & 7)) * 8;
      const int c1 = ((4 + lgrp) ^ (lrow & 7)) * 8;
      pa[qt][0] = *reinterpret_cast<const short8*>(&lds_p[w][lrow * 64 + c0]);
      pa[qt][1] = *reinterpret_cast<const short8*>(&lds_p[w][lrow * 64 + c1]);
    }

    // PV: A = pa (regs), B-frag = V^T rows; V read once per nf (both qt)
    __builtin_amdgcn_s_setprio(1);
#pragma unroll
    for (int nf = 0; nf < 4; ++nf) {
      const short8 vf0 = *reinterpret_cast<const short8*>(
          &ldsv[(nf * 16 + lrow) * 64 + ((lgrp) ^ (lrow & 7)) * 8]);
      const short8 vf1 = *reinterpret_cast<const short8*>(
          &ldsv[(nf * 16 + lrow) * 64 + ((4 + lgrp) ^ (lrow & 7)) * 8]);
#pragma unroll
      for (int qt = 0; qt < 2; ++qt) {
        oacc[qt][nf] = __builtin_amdgcn_mfma_f32_16x16x32_bf16(pa[qt][0], vf0, oacc[qt][nf], 0, 0, 0);
        oacc[qt][nf] = __builtin_amdgcn_mfma_f32_16x16x32_bf16(pa[qt][1], vf1, oacc[qt][nf], 0, 0, 0);
      }
    }
    __builtin_amdgcn_s_setprio(0);
  };

  stageK(kd0, kg); kg += 65536;
  stageV(vd0, vg); vg += 64;
  __syncthreads();

#pragma unroll 1
  for (int kb = 0; kb < nkb; kb += 2) {
    if (kb + 1 < nkb) { stageK(kd1, kg); kg += 65536; stageV(vd1, vg); vg += 64; }
    body(kb, lds_k[0], lds_v[0]);
    __syncthreads();
    if (kb + 1 >= nkb) break;
    if (kb + 2 < nkb) { stageK(kd0, kg); kg += 65536; stageV(vd0, vg); vg += 64; }
    body(kb + 1, lds_k[1], lds_v[1]);
    __syncthreads();
  }

  // epilogue: reduce l per qt, write O rows qw + qt*16 + lgrp*4 + r
  lsum0 += __shfl_xor(lsum0, 16, 64);
  lsum0 += __shfl_xor(lsum0, 32, 64);
  lsum1 += __shfl_xor(lsum1, 16, 64);
  lsum1 += __shfl_xor(lsum1, 32, 64);
#pragma unroll
  for (int qt = 0; qt < 2; ++qt) {
    const float lw = qt == 0 ? lsum0 : lsum1;
#pragma unroll
    for (int r = 0; r < 4; ++r) {
      const float linv = 1.0f / __shfl(lw, lgrp * 4 + r, 64);
      const int t = qw + qt * 16 + lgrp * 4 + r;
#pragma unroll
      for (int nf = 0; nf < 4; ++nf)
        O[base + (size_t)t * 1024 + nf * 16 + lrow] = f2bf(oacc[qt][nf][r] * linv);
    }
  }
}

// ---------------- launcher ----------------
extern "C" void kernel_launch(void* const* d_in, const int* in_sizes, int n_in,
                              void* d_out, int out_size, void* d_ws, size_t ws_size,
                              hipStream_t stream) {
  const float* x  = (const float*)d_in[0];
  const float* Wq = (const float*)d_in[1];
  const float* Wk = (const float*)d_in[2];
  const float* Wv = (const float*)d_in[3];
  const float* Wo = (const float*)d_in[4];

  uint8_t* ws = (uint8_t*)d_ws;
  short* xb  = (short*)(ws + 0);           // 8192x1024 bf16  (16 MiB)
  short* wqb = (short*)(ws + 16777216);    // 4 x 1024x1024 bf16, contiguous
  short* wob = (short*)(ws + 23068672);
  short* Qb  = (short*)(ws + 25165824);    // 8192x1024 bf16
  short* Kb  = (short*)(ws + 41943040);
  short* Vt  = (short*)(ws + 58720256);    // [64 bh][64 d][2048 t] bf16
  short* Ob  = (short*)(ws + 75497472);
  if (ws_size < 92274688ull) return;  // fail loudly (output stays poisoned)

  const float qscale = 0.125f * LOG2E;     // fold head-scale + log2e into W_Q

  cvt_f32_bf16<<<8192, 256, 0, stream>>>(x, xb, 2097152, 1.0f);
  cvt_weights<<<dim3(1024, 4), 256, 0, stream>>>(Wq, Wk, Wv, Wo, wqb, qscale);

  gemm_qkv<<<256, 512, 0, stream>>>(xb, wqb, Qb, Kb, Vt);
  attn_fwd<<<1024, 256, 0, stream>>>(Qb, Kb, Vt, Ob);
  gemm_out<<<256, 512, 0, stream>>>(Ob, wob, (float*)d_out);
}